// Round 4
// baseline (258.150 us; speedup 1.0000x reference)
//
#include <hip/hip_runtime.h>

// ---------------------------------------------------------------------------
// Fused windowed attention (CrossFormer-style SDA).
// B=2, D=256, H=W=256, window 8x8 -> 2048 windows, HEADS=8, DHEAD=32.
// One 512-thread block = 4 horizontally-adjacent windows (8 rows x 32 cols).
// XCD-pairing block remap so 256B HBM granules are shared within one XCD.
// bf16 MFMA 16x16x32 (GEMMs) + 16x16x16 (PV from registers), fp32 accum.
// ---------------------------------------------------------------------------

typedef __attribute__((ext_vector_type(8))) short bf16x8;
typedef __attribute__((ext_vector_type(4))) short bf16x4;
typedef __attribute__((ext_vector_type(4))) float f32x4;

#define LOG2E    1.44269504088896f
#define QK_SCALE 0.17677669529663687f  // 32^-0.5

__device__ __forceinline__ short f2b(float f) {
  union { float f; unsigned u; } v; v.f = f;
  unsigned r = v.u + 0x7FFFu + ((v.u >> 16) & 1u);  // RNE
  return (short)(r >> 16);
}

// pack two f32 -> one u32 of 2 bf16 (round-to-nearest, ties up): 3 VALU
__device__ __forceinline__ unsigned pk2(float a, float b) {
  union { float f; unsigned u; } ua, ub; ua.f = a; ub.f = b;
#if __has_builtin(__builtin_amdgcn_perm)
  return __builtin_amdgcn_perm(ub.u + 0x8000u, ua.u + 0x8000u, 0x07060302u);
#else
  return ((ua.u + 0x8000u) >> 16) | ((ub.u + 0x8000u) & 0xFFFF0000u);
#endif
}

__device__ __forceinline__ bf16x8 mk8(unsigned a, unsigned b, unsigned c, unsigned d) {
  union { unsigned u[4]; bf16x8 v; } x; x.u[0] = a; x.u[1] = b; x.u[2] = c; x.u[3] = d;
  return x.v;
}
__device__ __forceinline__ bf16x4 mk4(unsigned a, unsigned b) {
  union { unsigned u[2]; bf16x4 v; } x; x.u[0] = a; x.u[1] = b; return x.v;
}

__device__ __forceinline__ f32x4 mfma16(bf16x4 a, bf16x4 b, f32x4 c) {
#if __has_builtin(__builtin_amdgcn_mfma_f32_16x16x16bf16_1k)
  return __builtin_amdgcn_mfma_f32_16x16x16bf16_1k(a, b, c, 0, 0, 0);
#else
  f32x4 d;
  asm volatile("v_mfma_f32_16x16x16_bf16 %0, %1, %2, %3"
               : "=&v"(d) : "v"(a), "v"(b), "v"(c));
  return d;
#endif
}

// ---------------------------------------------------------------------------
// Prep A: convert+tile weights to bf16 MFMA-fragment order (vectorized x8).
// Layout: block (etile*8+kt) of 512 shorts; within: [lane][8] where
//   e = etile*16 + (lane&15), d = kt*32 + (lane>>4)*8 + el.
// q rows (e<256) get QK_SCALE*LOG2E folded in (softmax done in exp2 domain).
// ---------------------------------------------------------------------------
__global__ __launch_bounds__(256)
void wconv_kernel(const float* __restrict__ wqkv, const float* __restrict__ wout,
                  short* __restrict__ wq_t, short* __restrict__ wo_t) {
  int t = (blockIdx.x * 256 + threadIdx.x) * 8;
  if (t < 196608) {
    int blk = t >> 9, l = (t & 511) >> 3;
    int et = blk >> 3, kt = blk & 7;
    int e = et * 16 + (l & 15);
    int d = kt * 32 + (l >> 4) * 8;
    const float* src = wqkv + e * 256 + d;
    float sc = (e < 256) ? QK_SCALE * LOG2E : 1.0f;
    bf16x8 pk;
    #pragma unroll
    for (int el = 0; el < 8; ++el) pk[el] = f2b(src[el] * sc);
    *(bf16x8*)(wq_t + t) = pk;
  } else if (t < 262144) {
    int o = t - 196608;
    int blk = o >> 9, l = (o & 511) >> 3;
    int dt = blk >> 3, kt = blk & 7;
    int dout = dt * 16 + (l & 15);
    int e = kt * 32 + (l >> 4) * 8;
    const float* src = wout + dout * 256 + e;
    bf16x8 pk;
    #pragma unroll
    for (int el = 0; el < 8; ++el) pk[el] = f2b(src[el]);
    *(bf16x8*)(wo_t + o) = pk;
  }
}

// ---------------------------------------------------------------------------
// Prep B: DPB MLP. One wave per grid position (289 blocks).
// ---------------------------------------------------------------------------
__device__ __forceinline__ float wave_sum64(float v) {
  v += __shfl_xor(v, 1);  v += __shfl_xor(v, 2);  v += __shfl_xor(v, 4);
  v += __shfl_xor(v, 8);  v += __shfl_xor(v, 16); v += __shfl_xor(v, 32);
  return v;
}

__global__ __launch_bounds__(64)
void dpb_kernel(const float* __restrict__ w1, const float* __restrict__ b1,
                const float* __restrict__ g1, const float* __restrict__ be1,
                const float* __restrict__ w2, const float* __restrict__ b2,
                const float* __restrict__ g2, const float* __restrict__ be2,
                const float* __restrict__ w3, const float* __restrict__ b3,
                const float* __restrict__ g3, const float* __restrict__ be3,
                const float* __restrict__ w4, const float* __restrict__ b4,
                float* __restrict__ sb) {
  __shared__ float h[64];
  __shared__ float wbuf[4096];
  const int f = threadIdx.x;
  const int pos = blockIdx.x;
  const float py = (float)(pos / 17) - 8.0f;
  const float px = (float)(pos % 17) - 8.0f;

  float a = py * w1[2 * f] + px * w1[2 * f + 1] + b1[f];
  {
    float m = wave_sum64(a) * (1.f / 64.f);
    float d = a - m;
    float var = wave_sum64(d * d) * (1.f / 64.f);
    a = fmaxf(d * rsqrtf(var + 1e-5f) * g1[f] + be1[f], 0.f);
  }
  h[f] = a;
  __threadfence_block();

  #pragma unroll 8
  for (int k = 0; k < 64; ++k) wbuf[k * 64 + f] = w2[k * 64 + f];
  __threadfence_block();
  float acc = b2[f];
  #pragma unroll 8
  for (int k = 0; k < 64; ++k) {
    int g = (k + f) & 63;
    acc += wbuf[f * 64 + g] * h[g];
  }
  {
    float m = wave_sum64(acc) * (1.f / 64.f);
    float d = acc - m;
    float var = wave_sum64(d * d) * (1.f / 64.f);
    acc = fmaxf(d * rsqrtf(var + 1e-5f) * g2[f] + be2[f], 0.f);
  }
  __threadfence_block();
  h[f] = acc;
  __threadfence_block();

  #pragma unroll 8
  for (int k = 0; k < 64; ++k) wbuf[k * 64 + f] = w3[k * 64 + f];
  __threadfence_block();
  float acc3 = b3[f];
  #pragma unroll 8
  for (int k = 0; k < 64; ++k) {
    int g = (k + f) & 63;
    acc3 += wbuf[f * 64 + g] * h[g];
  }
  {
    float m = wave_sum64(acc3) * (1.f / 64.f);
    float d = acc3 - m;
    float var = wave_sum64(d * d) * (1.f / 64.f);
    acc3 = fmaxf(d * rsqrtf(var + 1e-5f) * g3[f] + be3[f], 0.f);
  }
  float o = wave_sum64(w4[f] * acc3);
  if (f == 0) sb[pos] = o + b4[0];
}

// ---------------------------------------------------------------------------
// Prep C: expand raw MLP output (289) into MFMA-fragment-ordered bias table
// T[((it*4+jt)*64 + lane)*4 + jj] = sb[(iy-jy+7)*15 + (ix-jx+7)] * LOG2E
// where i = it*16 + (lane&15), j = jt*16 + (lane>>4)*4 + jj.
// ---------------------------------------------------------------------------
__global__ __launch_bounds__(512)
void expand_kernel(const float* __restrict__ sb, float* __restrict__ tblf) {
  int idx = blockIdx.x * 512 + threadIdx.x;   // 8 blocks -> 4096
  int it = idx >> 10, jt = (idx >> 8) & 3, ln = (idx >> 2) & 63, jj = idx & 3;
  int rr = ln & 15, gg = ln >> 4;
  int i = it * 16 + rr;
  int j = jt * 16 + gg * 4 + jj;
  int dy = (i >> 3) - (j >> 3) + 7;
  int dx = (i & 7) - (j & 7) + 7;
  tblf[idx] = sb[dy * 15 + dx] * LOG2E;
}

// ---------------------------------------------------------------------------
// Main fused kernel. LDS (bytes), total 163840 (160KiB exactly):
//   [0     ,131072) XA [256 pos][256 ch] bf16, XASWZ swizzle.
//                   xn before each window's QKV; overwritten by ao after PV.
//   [131072,163840) per-wave 4KB f32 scratch (q -> k -> vT round-trips);
//                   overlaid pre-loop by LN double-buffered partial sums.
// ---------------------------------------------------------------------------
#define SM_XA   0
#define SM_WS   131072
#define SM_SIZE 163840
#define XASWZ(p) ((((p) & 7) << 4) ^ ((((p) >> 3) & 3) << 7))

__global__ __launch_bounds__(512, 2)
void attn_kernel(const float* __restrict__ x, const float* __restrict__ gnorm,
                 const float* __restrict__ bnorm, const short* __restrict__ wq_t,
                 const short* __restrict__ wo_t, const float* __restrict__ bout,
                 const float* __restrict__ tblf, float* __restrict__ out) {
  __shared__ __align__(16) char smem[SM_SIZE];
  const int t = threadIdx.x;
  const int lane = t & 63;
  const int w = t >> 6;          // wave id 0..7 == head id
  const int r = lane & 15;
  const int gq = lane >> 4;

  // XCD pairing remap: XCD (bid&7) owns 64 consecutive window-groups, so the
  // two blocks sharing each 256B HBM granule are same-XCD and co-resident.
  const int lb  = (blockIdx.x & 7) * 64 + (blockIdx.x >> 3);
  const int b   = lb >> 8;
  const int wh  = (lb >> 3) & 31;
  const int ww4 = lb & 7;
  const int R = wh * 8, C = ww4 * 32;

  // ---- bias table -> registers (fragment order, reused all 4 windows) ----
  f32x4 bias[4][4];
  #pragma unroll
  for (int it = 0; it < 4; ++it)
    #pragma unroll
    for (int jt = 0; jt < 4; ++jt)
      bias[it][jt] = *(const f32x4*)(tblf + (((it * 4 + jt) * 64 + lane) << 2));

  // ---- channel-first LayerNorm, 4 passes (2 rows x 32 cols each) ----
  const int n = lane;
  const int d0 = w * 32;
  #pragma unroll 1
  for (int h = 0; h < 4; ++h) {
    const float* xb = x + (((size_t)(b * 256 + d0)) << 16) + (R + 2 * h) * 256 + C;
    const int off = (n >> 5) * 256 + (n & 31);
    float xv[32];
    float s1 = 0.f, s2v = 0.f;
    #pragma unroll
    for (int i = 0; i < 32; ++i) {
      float v = xb[((size_t)i << 16) + off];
      xv[i] = v; s1 += v; s2v += v * v;
    }
    float* sums  = (float*)(smem + SM_WS + (h & 1) * 8192);  // dbuf partials
    float* sumsq = sums + 512;
    sums[w * 64 + n] = s1;
    sumsq[w * 64 + n] = s2v;
    __syncthreads();
    float a = 0.f, q2 = 0.f;
    #pragma unroll
    for (int dg = 0; dg < 8; ++dg) {
      a  += sums[dg * 64 + n];
      q2 += sumsq[dg * 64 + n];
    }
    float mean = a * (1.f / 256.f);
    float var = q2 * (1.f / 256.f) - mean * mean;   // biased, matches jnp.var
    float rstd = rsqrtf(var + 1e-5f);
    int p = h * 64 + n;
    #pragma unroll
    for (int c = 0; c < 4; ++c) {
      float xn[8];
      #pragma unroll
      for (int e = 0; e < 8; ++e) {
        int d = d0 + c * 8 + e;
        xn[e] = (xv[c * 8 + e] - mean) * rstd * gnorm[d] + bnorm[d];
      }
      *(bf16x8*)(smem + SM_XA + (p << 9) + ((((d0 + c * 8) << 1)) ^ XASWZ(p))) =
          mk8(pk2(xn[0], xn[1]), pk2(xn[2], xn[3]), pk2(xn[4], xn[5]), pk2(xn[6], xn[7]));
    }
  }
  __syncthreads();   // xn complete; LN scratch dead -> per-wave ws usable

  const f32x4 vzero = {0.f, 0.f, 0.f, 0.f};
  char* ws = smem + SM_WS + w * 4096;

  // QKV GEMM: pass PP (0=q,1=k,2=v) for window `win` -> ACC[4][2]
  #define QKV_PASS(PP, ACC)                                                     \
    {                                                                           \
      _Pragma("unroll")                                                         \
      for (int mt = 0; mt < 4; ++mt)                                            \
        _Pragma("unroll")                                                       \
        for (int nt = 0; nt < 2; ++nt) ACC[mt][nt] = vzero;                     \
      _Pragma("unroll")                                                         \
      for (int kt = 0; kt < 8; ++kt) {                                          \
        bf16x8 bfr0 = *(const bf16x8*)(wq_t + (((((PP) * 16 + w * 2 + 0) * 8 + kt) << 9) + lane * 8)); \
        bf16x8 bfr1 = *(const bf16x8*)(wq_t + (((((PP) * 16 + w * 2 + 1) * 8 + kt) << 9) + lane * 8)); \
        bf16x8 afr[4];                                                          \
        _Pragma("unroll")                                                       \
        for (int mt = 0; mt < 4; ++mt) {                                        \
          int pmt = (mt * 2 + (r >> 3)) * 32 + win * 8 + (r & 7);               \
          afr[mt] = *(const bf16x8*)(smem + SM_XA + (pmt << 9) + ((((kt * 32 + gq * 8) << 1)) ^ XASWZ(pmt))); \
        }                                                                       \
        _Pragma("unroll")                                                       \
        for (int mt = 0; mt < 4; ++mt) {                                        \
          ACC[mt][0] = __builtin_amdgcn_mfma_f32_16x16x32_bf16(afr[mt], bfr0, ACC[mt][0], 0, 0, 0); \
          ACC[mt][1] = __builtin_amdgcn_mfma_f32_16x16x32_bf16(afr[mt], bfr1, ACC[mt][1], 0, 0, 0); \
        }                                                                       \
      }                                                                         \
    }

  // q/k C-tile -> f32 scratch [32 pos][32 dh] (swz: ^80 if pos&4) -> bf16x8
  // sim fragments via vector read + pk2. Write <=2-way, read bank-optimal.
  #define QK_RT(ACC, FRAGS)                                                     \
    _Pragma("unroll")                                                           \
    for (int hf = 0; hf < 2; ++hf) {                                            \
      _Pragma("unroll")                                                         \
      for (int mh = 0; mh < 2; ++mh) {                                          \
        _Pragma("unroll")                                                       \
        for (int nt = 0; nt < 2; ++nt)                                          \
          _Pragma("unroll")                                                     \
          for (int jj = 0; jj < 4; ++jj) {                                      \
            int pos_l = mh * 16 + gq * 4 + jj;                                  \
            int dh = nt * 16 + r;                                               \
            *(float*)(ws + (((pos_l << 7) + (dh << 2)) ^ ((pos_l & 4) * 20))) = \
                ACC[2 * hf + mh][nt][jj];                                       \
          }                                                                     \
      }                                                                         \
      __threadfence_block();                                                    \
      _Pragma("unroll")                                                         \
      for (int th = 0; th < 2; ++th) {                                          \
        int pos_l = th * 16 + r;                                                \
        int swz = (pos_l & 4) * 20;                                             \
        f32x4 a0 = *(const f32x4*)(ws + (((pos_l << 7) + (gq << 5)) ^ swz));    \
        f32x4 a1 = *(const f32x4*)(ws + (((pos_l << 7) + (gq << 5) + 16) ^ swz)); \
        FRAGS[2 * hf + th] = mk8(pk2(a0[0], a0[1]), pk2(a0[2], a0[3]),          \
                                 pk2(a1[0], a1[1]), pk2(a1[2], a1[3]));         \
      }                                                                         \
      __threadfence_block();                                                    \
    }

  #pragma unroll 1
  for (int win = 0; win < 4; ++win) {
    bf16x8 qf[4], kf[4];
    {
      f32x4 acc[4][2];
      QKV_PASS(0, acc);
      QK_RT(acc, qf);
    }
    {
      f32x4 acc[4][2];
      QKV_PASS(1, acc);
      QK_RT(acc, kf);
    }

    // ---- sim^T = K.Q^T : lane (r,gq) holds S[i=it*16+r][j=jt*16+gq*4+jj]
    f32x4 s2[4][4];
    #pragma unroll
    for (int jt = 0; jt < 4; ++jt)
      #pragma unroll
      for (int it = 0; it < 4; ++it)
        s2[jt][it] = __builtin_amdgcn_mfma_f32_16x16x32_bf16(kf[jt], qf[it], vzero, 0, 0, 0);

    // ---- bias (registers) + softmax over j; values already x LOG2E ----
    #pragma unroll
    for (int it = 0; it < 4; ++it) {
      float m0 = -1e30f;
      #pragma unroll
      for (int jt = 0; jt < 4; ++jt)
        #pragma unroll
        for (int jj = 0; jj < 4; ++jj) {
          s2[jt][it][jj] += bias[it][jt][jj];
          m0 = fmaxf(m0, s2[jt][it][jj]);
        }
      m0 = fmaxf(m0, __shfl_xor(m0, 16));
      m0 = fmaxf(m0, __shfl_xor(m0, 32));
      float sum = 0.f;
      #pragma unroll
      for (int jt = 0; jt < 4; ++jt)
        #pragma unroll
        for (int jj = 0; jj < 4; ++jj) {
          float e = exp2f(s2[jt][it][jj] - m0);
          s2[jt][it][jj] = e; sum += e;
        }
      sum += __shfl_xor(sum, 16);
      sum += __shfl_xor(sum, 32);
      float pinv = 1.0f / sum;
      #pragma unroll
      for (int jt = 0; jt < 4; ++jt)
        #pragma unroll
        for (int jj = 0; jj < 4; ++jj) s2[jt][it][jj] *= pinv;
    }
    // pack P -> bf16 B-fragments of 16x16x16
    bf16x4 ppk[4][4];
    #pragma unroll
    for (int kt = 0; kt < 4; ++kt)
      #pragma unroll
      for (int it = 0; it < 4; ++it)
        ppk[kt][it] = mk4(pk2(s2[kt][it][0], s2[kt][it][1]),
                          pk2(s2[kt][it][2], s2[kt][it][3]));

    // ---- v ----
    f32x4 vacc[4][2];
    QKV_PASS(2, vacc);

    // ---- vT halves (f32 scratch [32 dh][32 pos], swz bits from dh) + PV ----
    f32x4 o2[2][4];
    #pragma unroll
    for (int mtD = 0; mtD < 2; ++mtD)
      #pragma unroll
      for (int it = 0; it < 4; ++it) o2[mtD][it] = vzero;
    #pragma unroll
    for (int hf = 0; hf < 2; ++hf) {
      #pragma unroll
      for (int mh = 0; mh < 2; ++mh)
        #pragma unroll
        for (int nt = 0; nt < 2; ++nt) {
          int dh = nt * 16 + r;
          int posb = mh * 16 + gq * 4;
          *(f32x4*)(ws + (((dh << 7) + (posb << 2)) ^ (((dh & 1) << 6) | ((dh & 2) << 3)))) =
              vacc[2 * hf + mh][nt];
        }
      __threadfence_block();
      #pragma unroll
      for (int ktl = 0; ktl < 2; ++ktl) {
        bf16x4 va[2];
        #pragma unroll
        for (int mtD = 0; mtD < 2; ++mtD) {
          int dh = mtD * 16 + r;
          f32x4 vv = *(const f32x4*)(ws + (((dh << 7) + ((ktl * 16 + gq * 4) << 2)) ^
                                           (((dh & 1) << 6) | ((dh & 2) << 3))));
          va[mtD] = mk4(pk2(vv[0], vv[1]), pk2(vv[2], vv[3]));
        }
        #pragma unroll
        for (int mtD = 0; mtD < 2; ++mtD)
          #pragma unroll
          for (int it = 0; it < 4; ++it)
            o2[mtD][it] = mfma16(va[mtD], ppk[2 * hf + ktl][it], o2[mtD][it]);
      }
      __threadfence_block();
    }

    __syncthreads();   // all waves done reading this window's xn rows

    // ---- ao into XA (overwrites this window's xn rows) ----
    #pragma unroll
    for (int mtD = 0; mtD < 2; ++mtD)
      #pragma unroll
      for (int it = 0; it < 4; ++it) {
        int i = it * 16 + r;
        int p = ((i >> 3) << 5) + (win << 3) + (i & 7);
        int e = (w << 5) + (mtD << 4) + (gq << 2);
        *(bf16x4*)(smem + SM_XA + (p << 9) + (((e << 1)) ^ XASWZ(p))) =
            mk4(pk2(o2[mtD][it][0], o2[mtD][it][1]), pk2(o2[mtD][it][2], o2[mtD][it][3]));
      }
  }
  __syncthreads();   // all ao ready

  // ---- out-proj: C[p][dout] = ao . wo^T; wave w owns dout [32w,32w+32).
  //      Per-lane f32x4 = 4 consecutive pixels -> vector global stores.
  bf16x8 woB[2][8];
  #pragma unroll
  for (int nt = 0; nt < 2; ++nt)
    #pragma unroll
    for (int kt = 0; kt < 8; ++kt)
      woB[nt][kt] = *(const bf16x8*)(wo_t + ((((w * 2 + nt) * 8 + kt) << 9) + lane * 8));
  float bov[2];
  bov[0] = bout[w * 32 + r];
  bov[1] = bout[w * 32 + 16 + r];

  #pragma unroll 1
  for (int ck = 0; ck < 4; ++ck) {
    f32x4 c3[4][2];
    #pragma unroll
    for (int mt = 0; mt < 4; ++mt)
      #pragma unroll
      for (int nt = 0; nt < 2; ++nt) c3[mt][nt] = vzero;
    #pragma unroll
    for (int kt = 0; kt < 8; ++kt) {
      bf16x8 af[4];
      #pragma unroll
      for (int mt = 0; mt < 4; ++mt) {
        int p = ck * 64 + mt * 16 + r;
        af[mt] = *(const bf16x8*)(smem + SM_XA + (p << 9) + ((((kt * 32 + gq * 8) << 1)) ^ XASWZ(p)));
      }
      #pragma unroll
      for (int mt = 0; mt < 4; ++mt)
        #pragma unroll
        for (int nt = 0; nt < 2; ++nt)
          c3[mt][nt] = __builtin_amdgcn_mfma_f32_16x16x32_bf16(af[mt], woB[nt][kt], c3[mt][nt], 0, 0, 0);
    }
    #pragma unroll
    for (int mt = 0; mt < 4; ++mt)
      #pragma unroll
      for (int nt = 0; nt < 2; ++nt) {
        int dout = w * 32 + nt * 16 + r;
        int prow = ck * 2 + (mt >> 1);
        int pcol = ((mt & 1) << 4) + (gq << 2);
        f32x4 v = c3[mt][nt];
        v[0] += bov[nt]; v[1] += bov[nt]; v[2] += bov[nt]; v[3] += bov[nt];
        *(f32x4*)(out + (((size_t)(b * 256 + dout)) << 16) + (R + prow) * 256 + C + pcol) = v;
      }
  }
  #undef QKV_PASS
  #undef QK_RT
}

// ---------------------------------------------------------------------------
extern "C" void kernel_launch(void* const* d_in, const int* in_sizes, int n_in,
                              void* d_out, int out_size, void* d_ws, size_t ws_size,
                              hipStream_t stream) {
  const float* x     = (const float*)d_in[0];
  const float* gnorm = (const float*)d_in[1];
  const float* bnorm = (const float*)d_in[2];
  const float* wqkv  = (const float*)d_in[3];
  const float* wout  = (const float*)d_in[4];
  const float* bout  = (const float*)d_in[5];
  const float* w1  = (const float*)d_in[6];
  const float* b1  = (const float*)d_in[7];
  const float* g1  = (const float*)d_in[8];
  const float* be1 = (const float*)d_in[9];
  const float* w2  = (const float*)d_in[10];
  const float* b2  = (const float*)d_in[11];
  const float* g2  = (const float*)d_in[12];
  const float* be2 = (const float*)d_in[13];
  const float* w3  = (const float*)d_in[14];
  const float* b3  = (const float*)d_in[15];
  const float* g3  = (const float*)d_in[16];
  const float* be3 = (const float*)d_in[17];
  const float* w4  = (const float*)d_in[18];
  const float* b4  = (const float*)d_in[19];

  short* wq_t = (short*)d_ws;                           // 393216 B
  short* wo_t = wq_t + 196608;                          // 131072 B
  float* sb   = (float*)((char*)d_ws + 524288);         // 1156 B
  float* tblf = (float*)((char*)d_ws + 528384);         // 16384 B

  wconv_kernel<<<dim3(128), dim3(256), 0, stream>>>(wqkv, wout, wq_t, wo_t);
  dpb_kernel<<<dim3(289), dim3(64), 0, stream>>>(
      w1, b1, g1, be1, w2, b2, g2, be2, w3, b3, g3, be3, w4, b4, sb);
  expand_kernel<<<dim3(8), dim3(512), 0, stream>>>(sb, tblf);

  attn_kernel<<<dim3(512), dim3(512), 0, stream>>>(
      x, gnorm, bnorm, wq_t, wo_t, bout, tblf, (float*)d_out);
}